// Round 14
// baseline (211.928 us; speedup 1.0000x reference)
//
#include <hip/hip_runtime.h>
#include <cstdint>
#include <cstddef>

// Problem constants (fixed by the reference)
#define T_TOK 8192
#define DIM   1024   // D
#define FF    512    // F
#define NE    8      // experts
#define NSLOT 16384  // T*K
#define BM    128    // M-tile rows (both fast GEMMs)
#define MAXBLK (NSLOT / BM + NE)   // 136: worst-case Σ ceil(n_e/BM)

typedef short s16x8 __attribute__((ext_vector_type(8)));   // 8 bf16 (4 VGPRs) - MFMA A/B frag
typedef float f32x4 __attribute__((ext_vector_type(4)));   // MFMA C/D frag

// f32 -> bf16 (round-to-nearest-even), returns bits in low 16
__device__ __forceinline__ unsigned int f2bf(float f) {
    union { float f; unsigned int u; } v; v.f = f;
    return (v.u + 0x7FFFu + ((v.u >> 16) & 1u)) >> 16;
}
__device__ __forceinline__ float bf2f(unsigned short b) {
    union { unsigned int u; float f; } v; v.u = ((unsigned int)b) << 16;
    return v.f;
}
__device__ __forceinline__ int pack2(float a, float b) {
    return (int)f2bf(a) | ((int)f2bf(b) << 16);
}
__device__ __forceinline__ int4 cvt8(const float* p) {
    float4 x = *(const float4*)p;
    float4 y = *(const float4*)(p + 4);
    int4 r;
    r.x = pack2(x.x, x.y); r.y = pack2(x.z, x.w);
    r.z = pack2(y.x, y.y); r.w = pack2(y.z, y.w);
    return r;
}

// async global(per-lane addr) -> LDS(wave-uniform base + lane*16)
__device__ __forceinline__ void gload16(const unsigned short* g, unsigned short* l) {
    __builtin_amdgcn_global_load_lds(
        (const __attribute__((address_space(1))) void*)g,
        (__attribute__((address_space(3))) void*)l, 16, 0, 0);
}

// ---------------- routing (split kernels; no global memset needed) ----------------
// route_count: 64 blocks x 256 thr; per-block LDS counts -> partial[block*8+e]
__global__ __launch_bounds__(256) void route_count(const int* __restrict__ idx,
                                                   int* __restrict__ partial) {
    __shared__ int cnt[NE];
    const int tid = threadIdx.x;
    if (tid < NE) cnt[tid] = 0;
    __syncthreads();
    atomicAdd(&cnt[idx[blockIdx.x * 256 + tid]], 1);
    __syncthreads();
    if (tid < NE) partial[blockIdx.x * NE + tid] = cnt[tid];
}

// route_scan: 1 block, 64 thr: sum partials, build offsets/cursor + alive-y tables
__global__ void route_scan(const int* __restrict__ partial, int* offsets, int* cursor,
                           int* blk_e, int* blk_by) {
    __shared__ int counts_s[NE];
    const int tid = threadIdx.x;
    if (tid < NE) {
        int s = 0;
        for (int b = 0; b < 64; ++b) s += partial[b * NE + tid];
        counts_s[tid] = s;
    }
    __syncthreads();
    if (tid == 0) {
        int acc = 0, nb = 0;
        for (int e = 0; e < NE; ++e) {
            offsets[e] = acc; cursor[e] = acc;
            const int nby = (counts_s[e] + BM - 1) / BM;
            for (int b = 0; b < nby; ++b) { blk_e[nb] = e; blk_by[nb] = b; ++nb; }
            acc += counts_s[e];
        }
        offsets[NE] = acc;
        for (int b = nb; b < MAXBLK; ++b) { blk_e[b] = -1; blk_by[b] = 0; }
    }
}
__global__ void route_scatter(const int* __restrict__ idx, int* cursor,
                              int* row_slot, int* slot_pos) {
    int s = blockIdx.x * 256 + threadIdx.x;
    if (s < NSLOT) {
        int e = idx[s];
        int p = atomicAdd(&cursor[e], 1);
        row_slot[p] = s;
        slot_pos[s] = p;     // inverse map: slot -> compact row
    }
}

// ---------------- one-time f32 -> bf16 conversion (hidden + both weights) ----------------
__global__ void cvt_all(const float* __restrict__ h, const float* __restrict__ g,
                        const float* __restrict__ d,
                        unsigned short* __restrict__ hb, unsigned short* __restrict__ gb,
                        unsigned short* __restrict__ db) {
    const int N1 = T_TOK * DIM / 8;          // 1,048,576
    const int N2 = NE * 2 * FF * DIM / 8;    // 1,048,576
    const int N3 = NE * DIM * FF / 8;        //   524,288
    const int stride = gridDim.x * 256;
    for (int i = blockIdx.x * 256 + threadIdx.x; i < N1 + N2 + N3; i += stride) {
        const float* s; unsigned short* o; int j;
        if (i < N1)            { s = h; o = hb; j = i; }
        else if (i < N1 + N2)  { s = g; o = gb; j = i - N1; }
        else                   { s = d; o = db; j = i - N1 - N2; }
        *(int4*)(o + (size_t)j * 8) = cvt8(s + (size_t)j * 8);
    }
}

// ================= fast path: 2-phase dbuf (pointer-swap form), global_load_lds =================
// grid: 2D (bx fastest, by); pointer-swap dbuf measured faster than static unroll-2
// (65 vs 74.5 us) and than counted-vmcnt depth-2 (87 us) -- compiler schedules it best.

// GEMM1: act = silu(X Wg^T) * (X Wu^T).  tile 128 rows x 64 act-cols (g+u), BK=64, 16 K-steps.
// grid (FF/64=8, MAXBLK); 256 thr = 4 waves (2M x 2N)
__global__ __launch_bounds__(256) void gemm1_bf16(
    const unsigned short* __restrict__ hb,    // [T, D] bf16
    const unsigned short* __restrict__ gupb,  // [E, 2F, D] bf16
    const int* __restrict__ row_slot,
    const int* __restrict__ offsets,
    const int* __restrict__ blk_e,
    const int* __restrict__ blk_by,
    unsigned short* __restrict__ act)         // [NSLOT, F] bf16
{
    const int e = blk_e[blockIdx.y];
    if (e < 0) return;
    const int bx      = blockIdx.x;
    const int lby     = blk_by[blockIdx.y];
    const int rowbase = offsets[e] + lby * BM;
    const int rowlim  = offsets[e + 1] - 1;
    const int nrows   = min(BM, offsets[e + 1] - rowbase);

    __shared__ __align__(16) unsigned short Ab0[BM * 64], Ab1[BM * 64];   // 16 KB each
    __shared__ __align__(16) unsigned short Bb0[128 * 64], Bb1[128 * 64]; // 16 KB each

    const int tid  = threadIdx.x;
    const int lane = tid & 63;
    const int wv   = tid >> 6;
    const int wr   = wv >> 1, wc = wv & 1;

    int aoff[4];
#pragma unroll
    for (int i = 0; i < 4; ++i) {
        const int ch = tid + i * 256;          // 1024 chunks = 128 rows x 8 col-chunks
        const int r = ch >> 3, c = ch & 7;
        int grow = rowbase + r; if (grow > rowlim) grow = rowlim;
        const int tok = row_slot[grow] >> 1;
        aoff[i] = tok * DIM + ((c ^ (r & 7)) << 3);
    }
    int boff[4];
#pragma unroll
    for (int i = 0; i < 4; ++i) {
        const int ch = tid + i * 256;
        const int r = ch >> 3, c = ch & 7;
        const int gr = (r < 64) ? (bx * 64 + r) : (FF + bx * 64 + r - 64);
        boff[i] = e * (2 * FF * DIM) + gr * DIM + ((c ^ (r & 7)) << 3);
    }

    const f32x4 zf = {0.f, 0.f, 0.f, 0.f};
    f32x4 ag[4][2], au[4][2];
#pragma unroll
    for (int m = 0; m < 4; ++m)
#pragma unroll
        for (int n = 0; n < 2; ++n) { ag[m][n] = zf; au[m][n] = zf; }

    unsigned short *Ard = Ab0, *Awr = Ab1, *Brd = Bb0, *Bwr = Bb1;

    // prologue: stage K-step 0
#pragma unroll
    for (int i = 0; i < 4; ++i) gload16(hb + aoff[i],   Ard + (wv * 64 + i * 256) * 8);
#pragma unroll
    for (int i = 0; i < 4; ++i) gload16(gupb + boff[i], Brd + (wv * 64 + i * 256) * 8);
    __syncthreads();

#pragma unroll 1
    for (int t = 0; t < DIM / 64; ++t) {
        // issue next-tile loads into write buffer (overlaps with this tile's compute)
        if (t < DIM / 64 - 1) {
            const int kn = (t + 1) * 64;
#pragma unroll
            for (int i = 0; i < 4; ++i) gload16(hb + aoff[i] + kn,   Awr + (wv * 64 + i * 256) * 8);
#pragma unroll
            for (int i = 0; i < 4; ++i) gload16(gupb + boff[i] + kn, Bwr + (wv * 64 + i * 256) * 8);
        }
        const char* Abc = (const char*)Ard;
        const char* Bbc = (const char*)Brd;
#pragma unroll
        for (int kk = 0; kk < 2; ++kk) {
            const int kc = kk * 4 + (lane >> 4);
            s16x8 af[4], bg[2], bu[2];
#pragma unroll
            for (int m = 0; m < 4; ++m) {
                const int r = wr * 64 + m * 16 + (lane & 15);
                af[m] = *(const s16x8*)(Abc + r * 128 + ((kc ^ (r & 7)) << 4));
            }
#pragma unroll
            for (int n = 0; n < 2; ++n) {
                const int rg = wc * 32 + n * 16 + (lane & 15);
                bg[n] = *(const s16x8*)(Bbc + rg * 128 + ((kc ^ (rg & 7)) << 4));
                const int ru = rg + 64;
                bu[n] = *(const s16x8*)(Bbc + ru * 128 + ((kc ^ (ru & 7)) << 4));
            }
#pragma unroll
            for (int m = 0; m < 4; ++m)
#pragma unroll
                for (int n = 0; n < 2; ++n) {
                    ag[m][n] = __builtin_amdgcn_mfma_f32_16x16x32_bf16(af[m], bg[n], ag[m][n], 0, 0, 0);
                    au[m][n] = __builtin_amdgcn_mfma_f32_16x16x32_bf16(af[m], bu[n], au[m][n], 0, 0, 0);
                }
        }
        __syncthreads();   // drains vmcnt -> write buffer ready; read buffer free for re-stage
        unsigned short* tp;
        tp = Ard; Ard = Awr; Awr = tp;
        tp = Brd; Brd = Bwr; Bwr = tp;
    }

    // epilogue: act = silu(g)*u -> bf16
#pragma unroll
    for (int m = 0; m < 4; ++m)
#pragma unroll
        for (int n = 0; n < 2; ++n) {
            const int col = bx * 64 + wc * 32 + n * 16 + (lane & 15);
#pragma unroll
            for (int i = 0; i < 4; ++i) {
                const int rl = wr * 64 + m * 16 + ((lane >> 4) << 2) + i;
                if (rl < nrows) {
                    const float g = ag[m][n][i];
                    const float u = au[m][n][i];
                    const float a = (g / (1.f + __expf(-g))) * u;
                    act[(size_t)(rowbase + rl) * FF + col] = (unsigned short)f2bf(a);
                }
            }
        }
}

// GEMM2: outslot[p] = w_slot * (act_row @ down^T), bf16, COMPACT-row order (coalesced;
// r13 lesson: slot-ordered scatter stores cost more than the byte halving saved).
// tile 128 x 128, BK=64, 8 K-steps.  grid (DIM/128=8, MAXBLK); 256 thr = 4 waves (2M x 2N)
__global__ __launch_bounds__(256) void gemm2_slot(
    const unsigned short* __restrict__ act,   // [NSLOT, F] bf16
    const unsigned short* __restrict__ downb, // [E, D, F] bf16
    const int* __restrict__ row_slot,
    const int* __restrict__ offsets,
    const int* __restrict__ blk_e,
    const int* __restrict__ blk_by,
    const float* __restrict__ tkw,            // [T*K]
    unsigned short* __restrict__ outslot)     // [NSLOT, D] bf16, compact order
{
    const int e = blk_e[blockIdx.y];
    if (e < 0) return;
    const int bx      = blockIdx.x;
    const int lby     = blk_by[blockIdx.y];
    const int rowbase = offsets[e] + lby * BM;
    const int nrows   = min(BM, offsets[e + 1] - rowbase);
    const int rowlim  = offsets[e + 1] - 1;

    __shared__ __align__(16) unsigned short Ab0[BM * 64], Ab1[BM * 64];
    __shared__ __align__(16) unsigned short Bb0[128 * 64], Bb1[128 * 64];

    const int tid  = threadIdx.x;
    const int lane = tid & 63;
    const int wv   = tid >> 6;
    const int wr   = wv >> 1, wc = wv & 1;

    int aoff[4];
#pragma unroll
    for (int i = 0; i < 4; ++i) {
        const int ch = tid + i * 256;
        const int r = ch >> 3, c = ch & 7;
        int grow = rowbase + r; if (grow > rowlim) grow = rowlim;
        aoff[i] = grow * FF + ((c ^ (r & 7)) << 3);
    }
    int boff[4];
#pragma unroll
    for (int i = 0; i < 4; ++i) {
        const int ch = tid + i * 256;
        const int r = ch >> 3, c = ch & 7;
        boff[i] = e * (DIM * FF) + (bx * 128 + r) * FF + ((c ^ (r & 7)) << 3);
    }

    const f32x4 zf = {0.f, 0.f, 0.f, 0.f};
    f32x4 acc[4][4];
#pragma unroll
    for (int m = 0; m < 4; ++m)
#pragma unroll
        for (int n = 0; n < 4; ++n) acc[m][n] = zf;

    unsigned short *Ard = Ab0, *Awr = Ab1, *Brd = Bb0, *Bwr = Bb1;

#pragma unroll
    for (int i = 0; i < 4; ++i) gload16(act + aoff[i],   Ard + (wv * 64 + i * 256) * 8);
#pragma unroll
    for (int i = 0; i < 4; ++i) gload16(downb + boff[i], Brd + (wv * 64 + i * 256) * 8);
    __syncthreads();

#pragma unroll 1
    for (int t = 0; t < FF / 64; ++t) {
        if (t < FF / 64 - 1) {
            const int kn = (t + 1) * 64;
#pragma unroll
            for (int i = 0; i < 4; ++i) gload16(act + aoff[i] + kn,   Awr + (wv * 64 + i * 256) * 8);
#pragma unroll
            for (int i = 0; i < 4; ++i) gload16(downb + boff[i] + kn, Bwr + (wv * 64 + i * 256) * 8);
        }
        const char* Abc = (const char*)Ard;
        const char* Bbc = (const char*)Brd;
#pragma unroll
        for (int kk = 0; kk < 2; ++kk) {
            const int kc = kk * 4 + (lane >> 4);
            s16x8 af[4], bf[4];
#pragma unroll
            for (int m = 0; m < 4; ++m) {
                const int r = wr * 64 + m * 16 + (lane & 15);
                af[m] = *(const s16x8*)(Abc + r * 128 + ((kc ^ (r & 7)) << 4));
            }
#pragma unroll
            for (int n = 0; n < 4; ++n) {
                const int r = wc * 64 + n * 16 + (lane & 15);
                bf[n] = *(const s16x8*)(Bbc + r * 128 + ((kc ^ (r & 7)) << 4));
            }
#pragma unroll
            for (int m = 0; m < 4; ++m)
#pragma unroll
                for (int n = 0; n < 4; ++n)
                    acc[m][n] = __builtin_amdgcn_mfma_f32_16x16x32_bf16(af[m], bf[n], acc[m][n], 0, 0, 0);
        }
        __syncthreads();
        unsigned short* tp;
        tp = Ard; Ard = Awr; Awr = tp;
        tp = Brd; Brd = Bwr; Bwr = tp;
    }

    // epilogue: scale by slot weight, bf16 store at COMPACT (coalesced) location
#pragma unroll
    for (int m = 0; m < 4; ++m)
#pragma unroll
        for (int i = 0; i < 4; ++i) {
            const int rl = wr * 64 + m * 16 + ((lane >> 4) << 2) + i;
            if (rl < nrows) {
                const float w = tkw[row_slot[rowbase + rl]];
                unsigned short* o = outslot + (size_t)(rowbase + rl) * DIM + bx * 128 + wc * 64 + (lane & 15);
#pragma unroll
                for (int n = 0; n < 4; ++n)
                    o[n * 16] = (unsigned short)f2bf(acc[m][n][i] * w);
            }
        }
}

// combine: out[t] = outslot[pos(2t)] + outslot[pos(2t+1)]  (already weight-scaled, bf16)
// 32 MB gathered read (2 KB row granules) + 32 MB write
__global__ __launch_bounds__(256) void combine_k(
    const unsigned short* __restrict__ outslot,
    const int* __restrict__ slot_pos,
    float* __restrict__ out)
{
    const int i = blockIdx.x * 256 + threadIdx.x;   // [0, T*D/8)
    const int t = i >> 7;                            // DIM/8 = 128 chunks/token
    const int d = (i & 127) << 3;
    const int p0 = slot_pos[2 * t], p1 = slot_pos[2 * t + 1];
    const s16x8 a = *(const s16x8*)(outslot + (size_t)p0 * DIM + d);
    const s16x8 b = *(const s16x8*)(outslot + (size_t)p1 * DIM + d);
    float4 o0, o1;
    o0.x = bf2f((unsigned short)a[0]) + bf2f((unsigned short)b[0]);
    o0.y = bf2f((unsigned short)a[1]) + bf2f((unsigned short)b[1]);
    o0.z = bf2f((unsigned short)a[2]) + bf2f((unsigned short)b[2]);
    o0.w = bf2f((unsigned short)a[3]) + bf2f((unsigned short)b[3]);
    o1.x = bf2f((unsigned short)a[4]) + bf2f((unsigned short)b[4]);
    o1.y = bf2f((unsigned short)a[5]) + bf2f((unsigned short)b[5]);
    o1.z = bf2f((unsigned short)a[6]) + bf2f((unsigned short)b[6]);
    o1.w = bf2f((unsigned short)a[7]) + bf2f((unsigned short)b[7]);
    float* op = out + (size_t)t * DIM + d;
    *(float4*)op = o0;
    *(float4*)(op + 4) = o1;
}

// ================= fallback path (f32 in-kernel convert, atomic out) =================

__global__ __launch_bounds__(256) void moe_gemm1(
    const float* __restrict__ hidden, const float* __restrict__ gup,
    const int* __restrict__ row_slot, const int* __restrict__ offsets,
    unsigned short* __restrict__ act)
{
    const int e = blockIdx.z;
    const int row0 = offsets[e];
    const int n_e = offsets[e + 1] - row0;
    const int by = blockIdx.y;
    if (by * 128 >= n_e) return;
    const int bx = blockIdx.x;
    __shared__ __align__(16) unsigned short Abuf[128 * 64];
    __shared__ __align__(16) unsigned short Bbuf[128 * 64];
    char* Ab = (char*)Abuf; char* Bb = (char*)Bbuf;
    const int tid = threadIdx.x, lane = tid & 63, wv = tid >> 6;
    const int wr = wv >> 1, wc = wv & 1;
    const float* aptr[4]; const float* bptr[4]; int soff[4];
#pragma unroll
    for (int i = 0; i < 4; ++i) {
        const int chunk = tid + i * 256;
        const int r = chunk >> 3, c = chunk & 7;
        soff[i] = r * 128 + ((c ^ (r & 7)) << 4);
        int rr = by * 128 + r; if (rr >= n_e) rr = n_e - 1;
        const int slot = row_slot[row0 + rr];
        aptr[i] = hidden + (size_t)(slot >> 1) * DIM + c * 8;
        const int gr = (r < 64) ? (bx * 64 + r) : (FF + bx * 64 + (r - 64));
        bptr[i] = gup + (size_t)e * (2 * FF * DIM) + (size_t)gr * DIM + c * 8;
    }
    const f32x4 zf = {0.f, 0.f, 0.f, 0.f};
    f32x4 acc_g[4][2], acc_u[4][2];
#pragma unroll
    for (int m = 0; m < 4; ++m)
#pragma unroll
        for (int n = 0; n < 2; ++n) { acc_g[m][n] = zf; acc_u[m][n] = zf; }
    for (int k0 = 0; k0 < DIM; k0 += 64) {
        __syncthreads();
#pragma unroll
        for (int i = 0; i < 4; ++i) *(int4*)(Ab + soff[i]) = cvt8(aptr[i] + k0);
#pragma unroll
        for (int i = 0; i < 4; ++i) *(int4*)(Bb + soff[i]) = cvt8(bptr[i] + k0);
        __syncthreads();
#pragma unroll
        for (int kk = 0; kk < 2; ++kk) {
            const int kc = kk * 4 + (lane >> 4);
            s16x8 af[4], bg[2], bu[2];
#pragma unroll
            for (int m = 0; m < 4; ++m) {
                const int r = wr * 64 + m * 16 + (lane & 15);
                af[m] = *(const s16x8*)(Ab + r * 128 + ((kc ^ (r & 7)) << 4));
            }
#pragma unroll
            for (int n = 0; n < 2; ++n) {
                const int rg = wc * 32 + n * 16 + (lane & 15);
                bg[n] = *(const s16x8*)(Bb + rg * 128 + ((kc ^ (rg & 7)) << 4));
                const int ru = rg + 64;
                bu[n] = *(const s16x8*)(Bb + ru * 128 + ((kc ^ (ru & 7)) << 4));
            }
#pragma unroll
            for (int m = 0; m < 4; ++m)
#pragma unroll
                for (int n = 0; n < 2; ++n) {
                    acc_g[m][n] = __builtin_amdgcn_mfma_f32_16x16x32_bf16(af[m], bg[n], acc_g[m][n], 0, 0, 0);
                    acc_u[m][n] = __builtin_amdgcn_mfma_f32_16x16x32_bf16(af[m], bu[n], acc_u[m][n], 0, 0, 0);
                }
        }
    }
#pragma unroll
    for (int m = 0; m < 4; ++m)
#pragma unroll
        for (int n = 0; n < 2; ++n) {
            const int col = bx * 64 + wc * 32 + n * 16 + (lane & 15);
#pragma unroll
            for (int i = 0; i < 4; ++i) {
                const int rl = wr * 64 + m * 16 + ((lane >> 4) << 2) + i;
                const int rr = by * 128 + rl;
                if (rr < n_e) {
                    const float g = acc_g[m][n][i];
                    const float u = acc_u[m][n][i];
                    const float a = (g / (1.f + __expf(-g))) * u;
                    act[(size_t)(row0 + rr) * FF + col] = (unsigned short)f2bf(a);
                }
            }
        }
}

__global__ __launch_bounds__(256) void moe_gemm2(
    const unsigned short* __restrict__ act, const float* __restrict__ down,
    const int* __restrict__ row_slot, const int* __restrict__ offsets,
    const float* __restrict__ tkw, float* __restrict__ out)
{
    const int e = blockIdx.z;
    const int row0 = offsets[e];
    const int n_e = offsets[e + 1] - row0;
    const int by = blockIdx.y;
    if (by * 128 >= n_e) return;
    const int bx = blockIdx.x;
    __shared__ __align__(16) unsigned short Abuf[128 * 64];
    __shared__ __align__(16) unsigned short Bbuf[128 * 64];
    char* Ab = (char*)Abuf; char* Bb = (char*)Bbuf;
    const int tid = threadIdx.x, lane = tid & 63, wv = tid >> 6;
    const int wr = wv >> 1, wc = wv & 1;
    const unsigned short* aptr[4]; const float* bptr[4]; int soff[4];
#pragma unroll
    for (int i = 0; i < 4; ++i) {
        const int chunk = tid + i * 256;
        const int r = chunk >> 3, c = chunk & 7;
        soff[i] = r * 128 + ((c ^ (r & 7)) << 4);
        int rr = by * 128 + r; if (rr >= n_e) rr = n_e - 1;
        aptr[i] = act + (size_t)(row0 + rr) * FF + c * 8;
        bptr[i] = down + (size_t)e * (DIM * FF) + (size_t)(bx * 128 + r) * FF + c * 8;
    }
    const f32x4 zf = {0.f, 0.f, 0.f, 0.f};
    f32x4 acc[4][4];
#pragma unroll
    for (int m = 0; m < 4; ++m)
#pragma unroll
        for (int n = 0; n < 4; ++n) acc[m][n] = zf;
    for (int k0 = 0; k0 < FF; k0 += 64) {
        __syncthreads();
#pragma unroll
        for (int i = 0; i < 4; ++i) *(int4*)(Ab + soff[i]) = *(const int4*)(aptr[i] + k0);
#pragma unroll
        for (int i = 0; i < 4; ++i) *(int4*)(Bb + soff[i]) = cvt8(bptr[i] + k0);
        __syncthreads();
#pragma unroll
        for (int kk = 0; kk < 2; ++kk) {
            const int kc = kk * 4 + (lane >> 4);
            s16x8 af[4], bf[4];
#pragma unroll
            for (int m = 0; m < 4; ++m) {
                const int r = wr * 64 + m * 16 + (lane & 15);
                af[m] = *(const s16x8*)(Ab + r * 128 + ((kc ^ (r & 7)) << 4));
            }
#pragma unroll
            for (int n = 0; n < 4; ++n) {
                const int r = wc * 64 + n * 16 + (lane & 15);
                bf[n] = *(const s16x8*)(Bb + r * 128 + ((kc ^ (r & 7)) << 4));
            }
#pragma unroll
            for (int m = 0; m < 4; ++m)
#pragma unroll
                for (int n = 0; n < 4; ++n)
                    acc[m][n] = __builtin_amdgcn_mfma_f32_16x16x32_bf16(af[m], bf[n], acc[m][n], 0, 0, 0);
        }
    }
#pragma unroll
    for (int m = 0; m < 4; ++m)
#pragma unroll
        for (int i = 0; i < 4; ++i) {
            const int rl = wr * 64 + m * 16 + ((lane >> 4) << 2) + i;
            const int rr = by * 128 + rl;
            if (rr < n_e) {
                const int slot = row_slot[row0 + rr];
                const float w = tkw[slot];
                float* orow = out + (size_t)(slot >> 1) * DIM + bx * 128 + wc * 64 + (lane & 15);
#pragma unroll
                for (int n = 0; n < 4; ++n)
                    unsafeAtomicAdd(orow + n * 16, acc[m][n][i] * w);
            }
        }
}

extern "C" void kernel_launch(void* const* d_in, const int* in_sizes, int n_in,
                              void* d_out, int out_size, void* d_ws, size_t ws_size,
                              hipStream_t stream)
{
    const float* hidden = (const float*)d_in[0];
    const int*   idx    = (const int*)  d_in[1];
    const float* tkw    = (const float*)d_in[2];
    const float* gup    = (const float*)d_in[3];
    const float* down   = (const float*)d_in[4];
    float* out = (float*)d_out;

    // workspace layout
    const size_t ACT = (size_t)NSLOT * FF * 2;        // 16 MB
    const size_t HB  = (size_t)T_TOK * DIM * 2;       // 16 MB
    const size_t GB  = (size_t)NE * 2 * FF * DIM * 2; // 16 MB
    const size_t DB  = (size_t)NE * DIM * FF * 2;     //  8 MB
    const size_t RS  = (size_t)NSLOT * 4;             // 64 KB (row_slot)
    const size_t SP  = (size_t)NSLOT * 4;             // 64 KB (slot_pos)
    const size_t CTRL = 8192;                         // offsets + blk tables + partials
    const size_t OSB = (size_t)NSLOT * DIM * 2;       // 32 MB (bf16 scaled outslot)
    char* ws = (char*)d_ws;
    unsigned short* act = (unsigned short*)ws;

    const size_t base_need = ACT + HB + GB + DB + RS + SP + CTRL;
    int mode;                       // 1: bf16 scaled slot path, 0: legacy atomic
    if      (ws_size >= base_need + OSB) mode = 1;
    else if (ws_size >= ACT + RS + SP + CTRL) mode = 0;
    else mode = -1;
    if (mode < 0) return;

    unsigned short *hb = nullptr, *gb = nullptr, *db = nullptr;
    int *row_slot, *ctrl; unsigned short* outslot = nullptr;
    if (mode == 1) {
        hb = (unsigned short*)(ws + ACT);
        gb = (unsigned short*)(ws + ACT + HB);
        db = (unsigned short*)(ws + ACT + HB + GB);
        row_slot = (int*)(ws + ACT + HB + GB + DB);
        ctrl     = (int*)(ws + ACT + HB + GB + DB + RS + SP);
        outslot  = (unsigned short*)(ws + base_need);
    } else {
        row_slot = (int*)(ws + ACT);
        ctrl     = (int*)(ws + ACT + RS + SP);
    }
    int* slot_pos = row_slot + NSLOT;
    int* offsets = ctrl;                         // [NE+1] (16 slots reserved)
    int* blk_e   = ctrl + 16;                    // [MAXBLK]
    int* blk_by  = ctrl + 16 + MAXBLK;           // [MAXBLK]
    int* cursor  = ctrl + 16 + 2 * MAXBLK;       // [8]
    int* partial = cursor + 8;                   // [64*8]

    if (mode == 0)
        hipMemsetAsync(out, 0, (size_t)T_TOK * DIM * sizeof(float), stream);

    route_count  <<<NSLOT / 256, 256, 0, stream>>>(idx, partial);
    route_scan   <<<1, 64, 0, stream>>>(partial, offsets, cursor, blk_e, blk_by);
    route_scatter<<<NSLOT / 256, 256, 0, stream>>>(idx, cursor, row_slot, slot_pos);

    if (mode == 1) {
        cvt_all<<<2048, 256, 0, stream>>>(hidden, gup, down, hb, gb, db);
        gemm1_bf16<<<dim3(FF / 64, MAXBLK), 256, 0, stream>>>(
            hb, gb, row_slot, offsets, blk_e, blk_by, act);
        gemm2_slot<<<dim3(DIM / 128, MAXBLK), 256, 0, stream>>>(
            act, db, row_slot, offsets, blk_e, blk_by, tkw, outslot);
        combine_k<<<T_TOK * DIM / 8 / 256, 256, 0, stream>>>(outslot, slot_pos, out);
    } else {
        moe_gemm1<<<dim3(FF / 64, 128, NE), 256, 0, stream>>>(hidden, gup, row_slot, offsets, act);
        moe_gemm2<<<dim3(DIM / 128, 128, NE), 256, 0, stream>>>(act, down, row_slot, offsets, tkw, out);
    }
}

// Round 15
// 206.060 us; speedup vs baseline: 1.0285x; 1.0285x over previous
//
#include <hip/hip_runtime.h>
#include <cstdint>
#include <cstddef>

// Problem constants (fixed by the reference)
#define T_TOK 8192
#define DIM   1024   // D
#define FF    512    // F
#define NE    8      // experts
#define NSLOT 16384  // T*K
#define BM    128    // M-tile rows (both fast GEMMs)
#define MAXBLK (NSLOT / BM + NE)   // 136: worst-case Σ ceil(n_e/BM)

typedef short s16x8 __attribute__((ext_vector_type(8)));   // 8 bf16 (4 VGPRs) - MFMA A/B frag
typedef float f32x4 __attribute__((ext_vector_type(4)));   // MFMA C/D frag

// f32 -> bf16 (round-to-nearest-even), returns bits in low 16
__device__ __forceinline__ unsigned int f2bf(float f) {
    union { float f; unsigned int u; } v; v.f = f;
    return (v.u + 0x7FFFu + ((v.u >> 16) & 1u)) >> 16;
}
__device__ __forceinline__ float bf2f(unsigned short b) {
    union { unsigned int u; float f; } v; v.u = ((unsigned int)b) << 16;
    return v.f;
}
__device__ __forceinline__ int pack2(float a, float b) {
    return (int)f2bf(a) | ((int)f2bf(b) << 16);
}
__device__ __forceinline__ int4 cvt8(const float* p) {
    float4 x = *(const float4*)p;
    float4 y = *(const float4*)(p + 4);
    int4 r;
    r.x = pack2(x.x, x.y); r.y = pack2(x.z, x.w);
    r.z = pack2(y.x, y.y); r.w = pack2(y.z, y.w);
    return r;
}

// async global(per-lane addr) -> LDS(wave-uniform base + lane*16)
__device__ __forceinline__ void gload16(const unsigned short* g, unsigned short* l) {
    __builtin_amdgcn_global_load_lds(
        (const __attribute__((address_space(1))) void*)g,
        (__attribute__((address_space(3))) void*)l, 16, 0, 0);
}

// ---------------- routing (split kernels; no global memset needed) ----------------
// route_count: 64 blocks x 256 thr; per-block LDS counts -> partial[block*8+e]
__global__ __launch_bounds__(256) void route_count(const int* __restrict__ idx,
                                                   int* __restrict__ partial) {
    __shared__ int cnt[NE];
    const int tid = threadIdx.x;
    if (tid < NE) cnt[tid] = 0;
    __syncthreads();
    atomicAdd(&cnt[idx[blockIdx.x * 256 + tid]], 1);
    __syncthreads();
    if (tid < NE) partial[blockIdx.x * NE + tid] = cnt[tid];
}

// route_scan: 1 block, 64 thr: sum partials, build offsets/cursor + alive-y tables
__global__ void route_scan(const int* __restrict__ partial, int* offsets, int* cursor,
                           int* blk_e, int* blk_by) {
    __shared__ int counts_s[NE];
    const int tid = threadIdx.x;
    if (tid < NE) {
        int s = 0;
        for (int b = 0; b < 64; ++b) s += partial[b * NE + tid];
        counts_s[tid] = s;
    }
    __syncthreads();
    if (tid == 0) {
        int acc = 0, nb = 0;
        for (int e = 0; e < NE; ++e) {
            offsets[e] = acc; cursor[e] = acc;
            const int nby = (counts_s[e] + BM - 1) / BM;
            for (int b = 0; b < nby; ++b) { blk_e[nb] = e; blk_by[nb] = b; ++nb; }
            acc += counts_s[e];
        }
        offsets[NE] = acc;
        for (int b = nb; b < MAXBLK; ++b) { blk_e[b] = -1; blk_by[b] = 0; }
    }
}
__global__ void route_scatter(const int* __restrict__ idx, int* cursor,
                              int* row_slot, int* slot_pos) {
    int s = blockIdx.x * 256 + threadIdx.x;
    if (s < NSLOT) {
        int e = idx[s];
        int p = atomicAdd(&cursor[e], 1);
        row_slot[p] = s;
        slot_pos[s] = p;     // inverse map: slot -> compact row
    }
}

// ---------------- one-time f32 -> bf16 conversion (hidden + both weights) ----------------
__global__ void cvt_all(const float* __restrict__ h, const float* __restrict__ g,
                        const float* __restrict__ d,
                        unsigned short* __restrict__ hb, unsigned short* __restrict__ gb,
                        unsigned short* __restrict__ db) {
    const int N1 = T_TOK * DIM / 8;          // 1,048,576
    const int N2 = NE * 2 * FF * DIM / 8;    // 1,048,576
    const int N3 = NE * DIM * FF / 8;        //   524,288
    const int stride = gridDim.x * 256;
    for (int i = blockIdx.x * 256 + threadIdx.x; i < N1 + N2 + N3; i += stride) {
        const float* s; unsigned short* o; int j;
        if (i < N1)            { s = h; o = hb; j = i; }
        else if (i < N1 + N2)  { s = g; o = gb; j = i - N1; }
        else                   { s = d; o = db; j = i - N1 - N2; }
        *(int4*)(o + (size_t)j * 8) = cvt8(s + (size_t)j * 8);
    }
}

// ================= fast path: 2-phase dbuf (pointer-swap form), global_load_lds =================
// grid: 2D (bx fastest, by); pointer-swap dbuf measured faster than static unroll-2
// (65 vs 74.5 us) and than counted-vmcnt depth-2 (87 us) -- compiler schedules it best.
// f32 outslot in COMPACT order + slot_pos combine measured faster than both bf16
// variants (206 vs 211.5/211.9 us): narrower 2B stores/gathers cost more than the
// bytes they save (intermediates partially L2/L3-absorbed).

// GEMM1: act = silu(X Wg^T) * (X Wu^T).  tile 128 rows x 64 act-cols (g+u), BK=64, 16 K-steps.
// grid (FF/64=8, MAXBLK); 256 thr = 4 waves (2M x 2N)
__global__ __launch_bounds__(256) void gemm1_bf16(
    const unsigned short* __restrict__ hb,    // [T, D] bf16
    const unsigned short* __restrict__ gupb,  // [E, 2F, D] bf16
    const int* __restrict__ row_slot,
    const int* __restrict__ offsets,
    const int* __restrict__ blk_e,
    const int* __restrict__ blk_by,
    unsigned short* __restrict__ act)         // [NSLOT, F] bf16
{
    const int e = blk_e[blockIdx.y];
    if (e < 0) return;
    const int bx      = blockIdx.x;
    const int lby     = blk_by[blockIdx.y];
    const int rowbase = offsets[e] + lby * BM;
    const int rowlim  = offsets[e + 1] - 1;
    const int nrows   = min(BM, offsets[e + 1] - rowbase);

    __shared__ __align__(16) unsigned short Ab0[BM * 64], Ab1[BM * 64];   // 16 KB each
    __shared__ __align__(16) unsigned short Bb0[128 * 64], Bb1[128 * 64]; // 16 KB each

    const int tid  = threadIdx.x;
    const int lane = tid & 63;
    const int wv   = tid >> 6;
    const int wr   = wv >> 1, wc = wv & 1;

    int aoff[4];
#pragma unroll
    for (int i = 0; i < 4; ++i) {
        const int ch = tid + i * 256;          // 1024 chunks = 128 rows x 8 col-chunks
        const int r = ch >> 3, c = ch & 7;
        int grow = rowbase + r; if (grow > rowlim) grow = rowlim;
        const int tok = row_slot[grow] >> 1;
        aoff[i] = tok * DIM + ((c ^ (r & 7)) << 3);
    }
    int boff[4];
#pragma unroll
    for (int i = 0; i < 4; ++i) {
        const int ch = tid + i * 256;
        const int r = ch >> 3, c = ch & 7;
        const int gr = (r < 64) ? (bx * 64 + r) : (FF + bx * 64 + r - 64);
        boff[i] = e * (2 * FF * DIM) + gr * DIM + ((c ^ (r & 7)) << 3);
    }

    const f32x4 zf = {0.f, 0.f, 0.f, 0.f};
    f32x4 ag[4][2], au[4][2];
#pragma unroll
    for (int m = 0; m < 4; ++m)
#pragma unroll
        for (int n = 0; n < 2; ++n) { ag[m][n] = zf; au[m][n] = zf; }

    unsigned short *Ard = Ab0, *Awr = Ab1, *Brd = Bb0, *Bwr = Bb1;

    // prologue: stage K-step 0
#pragma unroll
    for (int i = 0; i < 4; ++i) gload16(hb + aoff[i],   Ard + (wv * 64 + i * 256) * 8);
#pragma unroll
    for (int i = 0; i < 4; ++i) gload16(gupb + boff[i], Brd + (wv * 64 + i * 256) * 8);
    __syncthreads();

#pragma unroll 1
    for (int t = 0; t < DIM / 64; ++t) {
        // issue next-tile loads into write buffer (overlaps with this tile's compute)
        if (t < DIM / 64 - 1) {
            const int kn = (t + 1) * 64;
#pragma unroll
            for (int i = 0; i < 4; ++i) gload16(hb + aoff[i] + kn,   Awr + (wv * 64 + i * 256) * 8);
#pragma unroll
            for (int i = 0; i < 4; ++i) gload16(gupb + boff[i] + kn, Bwr + (wv * 64 + i * 256) * 8);
        }
        const char* Abc = (const char*)Ard;
        const char* Bbc = (const char*)Brd;
#pragma unroll
        for (int kk = 0; kk < 2; ++kk) {
            const int kc = kk * 4 + (lane >> 4);
            s16x8 af[4], bg[2], bu[2];
#pragma unroll
            for (int m = 0; m < 4; ++m) {
                const int r = wr * 64 + m * 16 + (lane & 15);
                af[m] = *(const s16x8*)(Abc + r * 128 + ((kc ^ (r & 7)) << 4));
            }
#pragma unroll
            for (int n = 0; n < 2; ++n) {
                const int rg = wc * 32 + n * 16 + (lane & 15);
                bg[n] = *(const s16x8*)(Bbc + rg * 128 + ((kc ^ (rg & 7)) << 4));
                const int ru = rg + 64;
                bu[n] = *(const s16x8*)(Bbc + ru * 128 + ((kc ^ (ru & 7)) << 4));
            }
#pragma unroll
            for (int m = 0; m < 4; ++m)
#pragma unroll
                for (int n = 0; n < 2; ++n) {
                    ag[m][n] = __builtin_amdgcn_mfma_f32_16x16x32_bf16(af[m], bg[n], ag[m][n], 0, 0, 0);
                    au[m][n] = __builtin_amdgcn_mfma_f32_16x16x32_bf16(af[m], bu[n], au[m][n], 0, 0, 0);
                }
        }
        __syncthreads();   // drains vmcnt -> write buffer ready; read buffer free for re-stage
        unsigned short* tp;
        tp = Ard; Ard = Awr; Awr = tp;
        tp = Brd; Brd = Bwr; Bwr = tp;
    }

    // epilogue: act = silu(g)*u -> bf16
#pragma unroll
    for (int m = 0; m < 4; ++m)
#pragma unroll
        for (int n = 0; n < 2; ++n) {
            const int col = bx * 64 + wc * 32 + n * 16 + (lane & 15);
#pragma unroll
            for (int i = 0; i < 4; ++i) {
                const int rl = wr * 64 + m * 16 + ((lane >> 4) << 2) + i;
                if (rl < nrows) {
                    const float g = ag[m][n][i];
                    const float u = au[m][n][i];
                    const float a = (g / (1.f + __expf(-g))) * u;
                    act[(size_t)(rowbase + rl) * FF + col] = (unsigned short)f2bf(a);
                }
            }
        }
}

// GEMM2: per-slot result = act_row @ down^T (UNSCALED), f32, COMPACT-row order.
// tile 128 x 128, BK=64, 8 K-steps.  grid (DIM/128=8, MAXBLK); 256 thr = 4 waves (2M x 2N)
__global__ __launch_bounds__(256) void gemm2_slot(
    const unsigned short* __restrict__ act,   // [NSLOT, F] bf16
    const unsigned short* __restrict__ downb, // [E, D, F] bf16
    const int* __restrict__ row_slot,
    const int* __restrict__ offsets,
    const int* __restrict__ blk_e,
    const int* __restrict__ blk_by,
    float* __restrict__ outslot)              // [NSLOT, D] f32, compact order
{
    const int e = blk_e[blockIdx.y];
    if (e < 0) return;
    const int bx      = blockIdx.x;
    const int lby     = blk_by[blockIdx.y];
    const int rowbase = offsets[e] + lby * BM;
    const int nrows   = min(BM, offsets[e + 1] - rowbase);
    const int rowlim  = offsets[e + 1] - 1;

    __shared__ __align__(16) unsigned short Ab0[BM * 64], Ab1[BM * 64];
    __shared__ __align__(16) unsigned short Bb0[128 * 64], Bb1[128 * 64];

    const int tid  = threadIdx.x;
    const int lane = tid & 63;
    const int wv   = tid >> 6;
    const int wr   = wv >> 1, wc = wv & 1;

    int aoff[4];
#pragma unroll
    for (int i = 0; i < 4; ++i) {
        const int ch = tid + i * 256;
        const int r = ch >> 3, c = ch & 7;
        int grow = rowbase + r; if (grow > rowlim) grow = rowlim;
        aoff[i] = grow * FF + ((c ^ (r & 7)) << 3);
    }
    int boff[4];
#pragma unroll
    for (int i = 0; i < 4; ++i) {
        const int ch = tid + i * 256;
        const int r = ch >> 3, c = ch & 7;
        boff[i] = e * (DIM * FF) + (bx * 128 + r) * FF + ((c ^ (r & 7)) << 3);
    }

    const f32x4 zf = {0.f, 0.f, 0.f, 0.f};
    f32x4 acc[4][4];
#pragma unroll
    for (int m = 0; m < 4; ++m)
#pragma unroll
        for (int n = 0; n < 4; ++n) acc[m][n] = zf;

    unsigned short *Ard = Ab0, *Awr = Ab1, *Brd = Bb0, *Bwr = Bb1;

#pragma unroll
    for (int i = 0; i < 4; ++i) gload16(act + aoff[i],   Ard + (wv * 64 + i * 256) * 8);
#pragma unroll
    for (int i = 0; i < 4; ++i) gload16(downb + boff[i], Brd + (wv * 64 + i * 256) * 8);
    __syncthreads();

#pragma unroll 1
    for (int t = 0; t < FF / 64; ++t) {
        if (t < FF / 64 - 1) {
            const int kn = (t + 1) * 64;
#pragma unroll
            for (int i = 0; i < 4; ++i) gload16(act + aoff[i] + kn,   Awr + (wv * 64 + i * 256) * 8);
#pragma unroll
            for (int i = 0; i < 4; ++i) gload16(downb + boff[i] + kn, Bwr + (wv * 64 + i * 256) * 8);
        }
        const char* Abc = (const char*)Ard;
        const char* Bbc = (const char*)Brd;
#pragma unroll
        for (int kk = 0; kk < 2; ++kk) {
            const int kc = kk * 4 + (lane >> 4);
            s16x8 af[4], bf[4];
#pragma unroll
            for (int m = 0; m < 4; ++m) {
                const int r = wr * 64 + m * 16 + (lane & 15);
                af[m] = *(const s16x8*)(Abc + r * 128 + ((kc ^ (r & 7)) << 4));
            }
#pragma unroll
            for (int n = 0; n < 4; ++n) {
                const int r = wc * 64 + n * 16 + (lane & 15);
                bf[n] = *(const s16x8*)(Bbc + r * 128 + ((kc ^ (r & 7)) << 4));
            }
#pragma unroll
            for (int m = 0; m < 4; ++m)
#pragma unroll
                for (int n = 0; n < 4; ++n)
                    acc[m][n] = __builtin_amdgcn_mfma_f32_16x16x32_bf16(af[m], bf[n], acc[m][n], 0, 0, 0);
        }
        __syncthreads();
        unsigned short* tp;
        tp = Ard; Ard = Awr; Awr = tp;
        tp = Brd; Brd = Bwr; Bwr = tp;
    }

    // epilogue: dense non-conflicting f32 stores to this block's (row, col-range)
#pragma unroll
    for (int m = 0; m < 4; ++m)
#pragma unroll
        for (int i = 0; i < 4; ++i) {
            const int rl = wr * 64 + m * 16 + ((lane >> 4) << 2) + i;
            if (rl < nrows) {
                float* o = outslot + (size_t)(rowbase + rl) * DIM + bx * 128 + wc * 64 + (lane & 15);
#pragma unroll
                for (int n = 0; n < 4; ++n) o[n * 16] = acc[m][n][i];
            }
        }
}

// combine: out[t] = w0 * outslot[pos(2t)] + w1 * outslot[pos(2t+1)]
__global__ __launch_bounds__(256) void combine_k(
    const float* __restrict__ outslot,
    const int* __restrict__ slot_pos,
    const float* __restrict__ tkw,
    float* __restrict__ out)
{
    const int i = blockIdx.x * 256 + threadIdx.x;   // [0, T*D/8)
    const int t = i >> 7;                            // DIM/8 = 128 chunks/token
    const int d = (i & 127) << 3;
    const int p0 = slot_pos[2 * t], p1 = slot_pos[2 * t + 1];
    const float w0 = tkw[2 * t],    w1 = tkw[2 * t + 1];
    const float* s0 = outslot + (size_t)p0 * DIM + d;
    const float* s1 = outslot + (size_t)p1 * DIM + d;
    float4 a0 = *(const float4*)s0, a1 = *(const float4*)(s0 + 4);
    float4 b0 = *(const float4*)s1, b1 = *(const float4*)(s1 + 4);
    float4 o0, o1;
    o0.x = w0*a0.x + w1*b0.x; o0.y = w0*a0.y + w1*b0.y;
    o0.z = w0*a0.z + w1*b0.z; o0.w = w0*a0.w + w1*b0.w;
    o1.x = w0*a1.x + w1*b1.x; o1.y = w0*a1.y + w1*b1.y;
    o1.z = w0*a1.z + w1*b1.z; o1.w = w0*a1.w + w1*b1.w;
    float* op = out + (size_t)t * DIM + d;
    *(float4*)op = o0;
    *(float4*)(op + 4) = o1;
}

// ================= fallback path (f32 in-kernel convert, atomic out) =================

__global__ __launch_bounds__(256) void moe_gemm1(
    const float* __restrict__ hidden, const float* __restrict__ gup,
    const int* __restrict__ row_slot, const int* __restrict__ offsets,
    unsigned short* __restrict__ act)
{
    const int e = blockIdx.z;
    const int row0 = offsets[e];
    const int n_e = offsets[e + 1] - row0;
    const int by = blockIdx.y;
    if (by * 128 >= n_e) return;
    const int bx = blockIdx.x;
    __shared__ __align__(16) unsigned short Abuf[128 * 64];
    __shared__ __align__(16) unsigned short Bbuf[128 * 64];
    char* Ab = (char*)Abuf; char* Bb = (char*)Bbuf;
    const int tid = threadIdx.x, lane = tid & 63, wv = tid >> 6;
    const int wr = wv >> 1, wc = wv & 1;
    const float* aptr[4]; const float* bptr[4]; int soff[4];
#pragma unroll
    for (int i = 0; i < 4; ++i) {
        const int chunk = tid + i * 256;
        const int r = chunk >> 3, c = chunk & 7;
        soff[i] = r * 128 + ((c ^ (r & 7)) << 4);
        int rr = by * 128 + r; if (rr >= n_e) rr = n_e - 1;
        const int slot = row_slot[row0 + rr];
        aptr[i] = hidden + (size_t)(slot >> 1) * DIM + c * 8;
        const int gr = (r < 64) ? (bx * 64 + r) : (FF + bx * 64 + (r - 64));
        bptr[i] = gup + (size_t)e * (2 * FF * DIM) + (size_t)gr * DIM + c * 8;
    }
    const f32x4 zf = {0.f, 0.f, 0.f, 0.f};
    f32x4 acc_g[4][2], acc_u[4][2];
#pragma unroll
    for (int m = 0; m < 4; ++m)
#pragma unroll
        for (int n = 0; n < 2; ++n) { acc_g[m][n] = zf; acc_u[m][n] = zf; }
    for (int k0 = 0; k0 < DIM; k0 += 64) {
        __syncthreads();
#pragma unroll
        for (int i = 0; i < 4; ++i) *(int4*)(Ab + soff[i]) = cvt8(aptr[i] + k0);
#pragma unroll
        for (int i = 0; i < 4; ++i) *(int4*)(Bb + soff[i]) = cvt8(bptr[i] + k0);
        __syncthreads();
#pragma unroll
        for (int kk = 0; kk < 2; ++kk) {
            const int kc = kk * 4 + (lane >> 4);
            s16x8 af[4], bg[2], bu[2];
#pragma unroll
            for (int m = 0; m < 4; ++m) {
                const int r = wr * 64 + m * 16 + (lane & 15);
                af[m] = *(const s16x8*)(Ab + r * 128 + ((kc ^ (r & 7)) << 4));
            }
#pragma unroll
            for (int n = 0; n < 2; ++n) {
                const int rg = wc * 32 + n * 16 + (lane & 15);
                bg[n] = *(const s16x8*)(Bb + rg * 128 + ((kc ^ (rg & 7)) << 4));
                const int ru = rg + 64;
                bu[n] = *(const s16x8*)(Bb + ru * 128 + ((kc ^ (ru & 7)) << 4));
            }
#pragma unroll
            for (int m = 0; m < 4; ++m)
#pragma unroll
                for (int n = 0; n < 2; ++n) {
                    acc_g[m][n] = __builtin_amdgcn_mfma_f32_16x16x32_bf16(af[m], bg[n], acc_g[m][n], 0, 0, 0);
                    acc_u[m][n] = __builtin_amdgcn_mfma_f32_16x16x32_bf16(af[m], bu[n], acc_u[m][n], 0, 0, 0);
                }
        }
    }
#pragma unroll
    for (int m = 0; m < 4; ++m)
#pragma unroll
        for (int n = 0; n < 2; ++n) {
            const int col = bx * 64 + wc * 32 + n * 16 + (lane & 15);
#pragma unroll
            for (int i = 0; i < 4; ++i) {
                const int rl = wr * 64 + m * 16 + ((lane >> 4) << 2) + i;
                const int rr = by * 128 + rl;
                if (rr < n_e) {
                    const float g = acc_g[m][n][i];
                    const float u = acc_u[m][n][i];
                    const float a = (g / (1.f + __expf(-g))) * u;
                    act[(size_t)(row0 + rr) * FF + col] = (unsigned short)f2bf(a);
                }
            }
        }
}

__global__ __launch_bounds__(256) void moe_gemm2(
    const unsigned short* __restrict__ act, const float* __restrict__ down,
    const int* __restrict__ row_slot, const int* __restrict__ offsets,
    const float* __restrict__ tkw, float* __restrict__ out)
{
    const int e = blockIdx.z;
    const int row0 = offsets[e];
    const int n_e = offsets[e + 1] - row0;
    const int by = blockIdx.y;
    if (by * 128 >= n_e) return;
    const int bx = blockIdx.x;
    __shared__ __align__(16) unsigned short Abuf[128 * 64];
    __shared__ __align__(16) unsigned short Bbuf[128 * 64];
    char* Ab = (char*)Abuf; char* Bb = (char*)Bbuf;
    const int tid = threadIdx.x, lane = tid & 63, wv = tid >> 6;
    const int wr = wv >> 1, wc = wv & 1;
    const unsigned short* aptr[4]; const float* bptr[4]; int soff[4];
#pragma unroll
    for (int i = 0; i < 4; ++i) {
        const int chunk = tid + i * 256;
        const int r = chunk >> 3, c = chunk & 7;
        soff[i] = r * 128 + ((c ^ (r & 7)) << 4);
        int rr = by * 128 + r; if (rr >= n_e) rr = n_e - 1;
        aptr[i] = act + (size_t)(row0 + rr) * FF + c * 8;
        bptr[i] = down + (size_t)e * (DIM * FF) + (size_t)(bx * 128 + r) * FF + c * 8;
    }
    const f32x4 zf = {0.f, 0.f, 0.f, 0.f};
    f32x4 acc[4][4];
#pragma unroll
    for (int m = 0; m < 4; ++m)
#pragma unroll
        for (int n = 0; n < 4; ++n) acc[m][n] = zf;
    for (int k0 = 0; k0 < FF; k0 += 64) {
        __syncthreads();
#pragma unroll
        for (int i = 0; i < 4; ++i) *(int4*)(Ab + soff[i]) = *(const int4*)(aptr[i] + k0);
#pragma unroll
        for (int i = 0; i < 4; ++i) *(int4*)(Bb + soff[i]) = cvt8(bptr[i] + k0);
        __syncthreads();
#pragma unroll
        for (int kk = 0; kk < 2; ++kk) {
            const int kc = kk * 4 + (lane >> 4);
            s16x8 af[4], bf[4];
#pragma unroll
            for (int m = 0; m < 4; ++m) {
                const int r = wr * 64 + m * 16 + (lane & 15);
                af[m] = *(const s16x8*)(Ab + r * 128 + ((kc ^ (r & 7)) << 4));
            }
#pragma unroll
            for (int n = 0; n < 4; ++n) {
                const int r = wc * 64 + n * 16 + (lane & 15);
                bf[n] = *(const s16x8*)(Bb + r * 128 + ((kc ^ (r & 7)) << 4));
            }
#pragma unroll
            for (int m = 0; m < 4; ++m)
#pragma unroll
                for (int n = 0; n < 4; ++n)
                    acc[m][n] = __builtin_amdgcn_mfma_f32_16x16x32_bf16(af[m], bf[n], acc[m][n], 0, 0, 0);
        }
    }
#pragma unroll
    for (int m = 0; m < 4; ++m)
#pragma unroll
        for (int i = 0; i < 4; ++i) {
            const int rl = wr * 64 + m * 16 + ((lane >> 4) << 2) + i;
            const int rr = by * 128 + rl;
            if (rr < n_e) {
                const int slot = row_slot[row0 + rr];
                const float w = tkw[slot];
                float* orow = out + (size_t)(slot >> 1) * DIM + bx * 128 + wc * 64 + (lane & 15);
#pragma unroll
                for (int n = 0; n < 4; ++n)
                    unsafeAtomicAdd(orow + n * 16, acc[m][n][i] * w);
            }
        }
}

extern "C" void kernel_launch(void* const* d_in, const int* in_sizes, int n_in,
                              void* d_out, int out_size, void* d_ws, size_t ws_size,
                              hipStream_t stream)
{
    const float* hidden = (const float*)d_in[0];
    const int*   idx    = (const int*)  d_in[1];
    const float* tkw    = (const float*)d_in[2];
    const float* gup    = (const float*)d_in[3];
    const float* down   = (const float*)d_in[4];
    float* out = (float*)d_out;

    // workspace layout
    const size_t ACT = (size_t)NSLOT * FF * 2;        // 16 MB
    const size_t HB  = (size_t)T_TOK * DIM * 2;       // 16 MB
    const size_t GB  = (size_t)NE * 2 * FF * DIM * 2; // 16 MB
    const size_t DB  = (size_t)NE * DIM * FF * 2;     //  8 MB
    const size_t RS  = (size_t)NSLOT * 4;             // 64 KB (row_slot)
    const size_t SP  = (size_t)NSLOT * 4;             // 64 KB (slot_pos)
    const size_t CTRL = 8192;                         // offsets + blk tables + partials
    const size_t OS32 = (size_t)NSLOT * DIM * 4;      // 64 MB (f32 outslot)
    char* ws = (char*)d_ws;
    unsigned short* act = (unsigned short*)ws;

    const size_t base_need = ACT + HB + GB + DB + RS + SP + CTRL;
    int mode;                       // 1: f32 slot path, 0: legacy atomic
    if      (ws_size >= base_need + OS32) mode = 1;
    else if (ws_size >= ACT + RS + SP + CTRL) mode = 0;
    else mode = -1;
    if (mode < 0) return;

    unsigned short *hb = nullptr, *gb = nullptr, *db = nullptr;
    int *row_slot, *ctrl; float* outslot = nullptr;
    if (mode == 1) {
        hb = (unsigned short*)(ws + ACT);
        gb = (unsigned short*)(ws + ACT + HB);
        db = (unsigned short*)(ws + ACT + HB + GB);
        row_slot = (int*)(ws + ACT + HB + GB + DB);
        ctrl     = (int*)(ws + ACT + HB + GB + DB + RS + SP);
        outslot  = (float*)(ws + base_need);
    } else {
        row_slot = (int*)(ws + ACT);
        ctrl     = (int*)(ws + ACT + RS + SP);
    }
    int* slot_pos = row_slot + NSLOT;
    int* offsets = ctrl;                         // [NE+1] (16 slots reserved)
    int* blk_e   = ctrl + 16;                    // [MAXBLK]
    int* blk_by  = ctrl + 16 + MAXBLK;           // [MAXBLK]
    int* cursor  = ctrl + 16 + 2 * MAXBLK;       // [8]
    int* partial = cursor + 8;                   // [64*8]

    if (mode == 0)
        hipMemsetAsync(out, 0, (size_t)T_TOK * DIM * sizeof(float), stream);

    route_count  <<<NSLOT / 256, 256, 0, stream>>>(idx, partial);
    route_scan   <<<1, 64, 0, stream>>>(partial, offsets, cursor, blk_e, blk_by);
    route_scatter<<<NSLOT / 256, 256, 0, stream>>>(idx, cursor, row_slot, slot_pos);

    if (mode == 1) {
        cvt_all<<<2048, 256, 0, stream>>>(hidden, gup, down, hb, gb, db);
        gemm1_bf16<<<dim3(FF / 64, MAXBLK), 256, 0, stream>>>(
            hb, gb, row_slot, offsets, blk_e, blk_by, act);
        gemm2_slot<<<dim3(DIM / 128, MAXBLK), 256, 0, stream>>>(
            act, db, row_slot, offsets, blk_e, blk_by, outslot);
        combine_k<<<T_TOK * DIM / 8 / 256, 256, 0, stream>>>(outslot, slot_pos, tkw, out);
    } else {
        moe_gemm1<<<dim3(FF / 64, 128, NE), 256, 0, stream>>>(hidden, gup, row_slot, offsets, act);
        moe_gemm2<<<dim3(DIM / 128, 128, NE), 256, 0, stream>>>(act, down, row_slot, offsets, tkw, out);
    }
}